// Round 1
// 689.143 us; speedup vs baseline: 1.0455x; 1.0455x over previous
//
#include <hip/hip_runtime.h>
#include <hip/hip_bf16.h>
#include <cstddef>

// Problem constants
#define B_ 2
#define C_ 256
#define HW_ 2304      // H*W = 48*48
#define CLS_ 20
#define N_ 2324       // CLS + HW
#define HDS_ 8
#define HD_ 32
#define SCALE_F 0.17677669529663687f
#define MR_ 0.3f
#define EPS_ 1e-5f
#define NT64 37        // ceil(N/64) 64-col tiles
#define NPAD 2368      // 37*64

typedef __attribute__((ext_vector_type(8))) short short8;
typedef __attribute__((ext_vector_type(4))) float f32x4;
typedef unsigned long long u64;

__device__ __forceinline__ short f2bf(float x) {
    union { __hip_bfloat16 b; short s; } u;
    u.b = __float2bfloat16(x);
    return u.s;
}
__device__ __forceinline__ u64 shfl_xor_u64(u64 v, int m) {
    unsigned lo = (unsigned)v, hi = (unsigned)(v >> 32);
    lo = (unsigned)__shfl_xor((int)lo, m, 64);
    hi = (unsigned)__shfl_xor((int)hi, m, 64);
    return ((u64)hi << 32) | lo;
}

// ---------------------------------------------------------------------------
// Merged weight transpose + bf16 convert: all 5 weights in one launch.
// W[K][N] -> Wt[N][K], scaled. 768 blocks total, range-dispatched.
// ---------------------------------------------------------------------------
__global__ __launch_bounds__(256) void wtrans_all_kernel(
    const float* __restrict__ Wq,  const float* __restrict__ Wkv,
    const float* __restrict__ Wp,  const float* __restrict__ W1,
    const float* __restrict__ W2,
    short* __restrict__ Wq_t, short* __restrict__ Wkv_t,
    short* __restrict__ Wp_t, short* __restrict__ W1_t,
    short* __restrict__ W2_t)
{
    __shared__ float S[32][33];
    int bid = blockIdx.x;
    const float* W; short* Wt; int K, Nn; float scale;
    if (bid < 64)       { W = Wq;  Wt = Wq_t;  K = 256;  Nn = 256;  scale = SCALE_F; }
    else if (bid < 192) { bid -= 64;  W = Wkv; Wt = Wkv_t; K = 256;  Nn = 512;  scale = 1.f; }
    else if (bid < 256) { bid -= 192; W = Wp;  Wt = Wp_t;  K = 256;  Nn = 256;  scale = 1.f; }
    else if (bid < 512) { bid -= 256; W = W1;  Wt = W1_t;  K = 256;  Nn = 1024; scale = 1.f; }
    else                { bid -= 512; W = W2;  Wt = W2_t;  K = 1024; Nn = 256;  scale = 1.f; }
    int nblk = Nn / 32;
    int n0 = (bid % nblk) * 32, k0 = (bid / nblk) * 32;
    int t = threadIdx.x;
    int nl = t & 31, kq = t >> 5;
    #pragma unroll
    for (int ii = 0; ii < 4; ++ii) {
        int k = kq + ii * 8;
        S[k][nl] = W[(size_t)(k0 + k) * Nn + n0 + nl] * scale;
    }
    __syncthreads();
    int kl = t & 31, nq = t >> 5;
    #pragma unroll
    for (int ii = 0; ii < 4; ++ii) {
        int n = nq + ii * 8;
        Wt[(size_t)(n0 + n) * K + k0 + kl] = f2bf(S[kl][n]);
    }
}

// ---------------------------------------------------------------------------
// Mask compress: (16, N, N) fp32 -> keep-bitmask (16, N, 37) uint64.
// bit=1 means keep (u >= MR). Cols >= N_ get 0. One wave per row.
// All 10 float4 loads hoisted ahead of the shfl trees (MLP).
// ---------------------------------------------------------------------------
__global__ __launch_bounds__(256) void mask_compress_kernel(
    const float* __restrict__ mask, u64* __restrict__ mbits)
{
    int rid = blockIdx.x * 4 + (threadIdx.x >> 6);   // (bh*N + row)
    int l = threadIdx.x & 63;
    const float* mrow = mask + (size_t)rid * N_;
    u64* orow = mbits + (size_t)rid * NT64;
    float4 uu[10];
    #pragma unroll
    for (int base = 0; base < 10; ++base) {
        int col = base * 256 + l * 4;
        if (col < N_) uu[base] = *(const float4*)&mrow[col];
        else { uu[base].x = -1.f; uu[base].y = -1.f; uu[base].z = -1.f; uu[base].w = -1.f; }
    }
    #pragma unroll
    for (int base = 0; base < 10; ++base) {
        float4 u = uu[base];
        unsigned nib = (u.x >= MR_ ? 1u : 0u) | (u.y >= MR_ ? 2u : 0u)
                     | (u.z >= MR_ ? 4u : 0u) | (u.w >= MR_ ? 8u : 0u);
        u64 part = (u64)nib << (4 * (l & 15));
        part |= shfl_xor_u64(part, 1);
        part |= shfl_xor_u64(part, 2);
        part |= shfl_xor_u64(part, 4);
        part |= shfl_xor_u64(part, 8);
        int widx = base * 4 + (l >> 4);
        if ((l & 15) == 0 && widx < NT64) orow[widx] = part;
    }
}

// ---------------------------------------------------------------------------
// LN over C=256 for x_query with NCHW->NHWC transpose; bf16 ln out + fp32 raw
// ---------------------------------------------------------------------------
__global__ __launch_bounds__(256) void lnq_kernel(
    const float* __restrict__ x, const float* __restrict__ g,
    const float* __restrict__ be, short* __restrict__ yln,
    float* __restrict__ yraw)
{
    int row = blockIdx.x;               // b*HW + n
    int b = row / HW_, n = row % HW_;
    int t = threadIdx.x;                // channel
    float v = x[((size_t)(b * C_ + t)) * HW_ + n];
    float s = v, s2 = v * v;
    #pragma unroll
    for (int off = 1; off < 64; off <<= 1) {
        s  += __shfl_xor(s,  off, 64);
        s2 += __shfl_xor(s2, off, 64);
    }
    __shared__ float rs[4], rs2[4];
    int w = t >> 6;
    if ((t & 63) == 0) { rs[w] = s; rs2[w] = s2; }
    __syncthreads();
    s  = rs[0] + rs[1] + rs[2] + rs[3];
    s2 = rs2[0] + rs2[1] + rs2[2] + rs2[3];
    float mean = s * (1.f / 256.f);
    float var  = s2 * (1.f / 256.f) - mean * mean;
    float inv  = rsqrtf(var + EPS_);
    yraw[(size_t)row * C_ + t] = v;
    yln [(size_t)row * C_ + t] = f2bf((v - mean) * inv * g[t] + be[t]);
}

// ---------------------------------------------------------------------------
// LN over last dim 256, fp32 in -> bf16 out.
// ---------------------------------------------------------------------------
__global__ __launch_bounds__(256) void ln_rows_kernel(
    const float* __restrict__ x, const float* __restrict__ g,
    const float* __restrict__ be, short* __restrict__ y)
{
    int row = blockIdx.x;
    int t = threadIdx.x;
    float v = x[(size_t)row * C_ + t];
    float s = v, s2 = v * v;
    #pragma unroll
    for (int off = 1; off < 64; off <<= 1) {
        s  += __shfl_xor(s,  off, 64);
        s2 += __shfl_xor(s2, off, 64);
    }
    __shared__ float rs[4], rs2[4];
    int w = t >> 6;
    if ((t & 63) == 0) { rs[w] = s; rs2[w] = s2; }
    __syncthreads();
    s  = rs[0] + rs[1] + rs[2] + rs[3];
    s2 = rs2[0] + rs2[1] + rs2[2] + rs2[3];
    float mean = s * (1.f / 256.f);
    float var  = s2 * (1.f / 256.f) - mean * mean;
    float inv  = rsqrtf(var + EPS_);
    y[(size_t)row * C_ + t] = f2bf((v - mean) * inv * g[t] + be[t]);
}

// ---------------------------------------------------------------------------
// bf16 MFMA GEMM: C[M,N] = A[M,K]@Wt[N,K]^T, A and Wt bf16, epilogue fp32.
// flags: 1 = gelu, 2 = bf16 output. 64x64 tile, BK=32, 4 waves.
// Register-prefetch pipeline: next K-tile's loads issue before the compute
// barrier so HBM latency hides under MFMA (T14).
// ---------------------------------------------------------------------------
__global__ __launch_bounds__(256) void gemm_bf16_kernel(
    const short* __restrict__ A, const short* __restrict__ Wt,
    void* __restrict__ Cc, int M, int Nn, int K,
    const float* __restrict__ bias, const float* __restrict__ res, int flags)
{
    __shared__ short As[64][40];   // [m][k]
    __shared__ short Ws[64][40];   // [n][k]
    const int t = threadIdx.x, w = t >> 6, l = t & 63;
    const int quad = l >> 4, c16 = l & 15;
    const int m0 = blockIdx.y * 64, n0 = blockIdx.x * 64;
    const int wm = (w >> 1) * 32, wn = (w & 1) * 32;
    const int sr = t >> 2, sk = (t & 3) * 8;
    const f32x4 cz = {0.f, 0.f, 0.f, 0.f};
    f32x4 acc[2][2] = {{cz, cz}, {cz, cz}};
    int ga = m0 + sr; if (ga >= M) ga = M - 1;  // clamp; garbage rows unused
    short8 av = *(const short8*)&A[(size_t)ga * K + sk];
    short8 wv = *(const short8*)&Wt[(size_t)(n0 + sr) * K + sk];
    for (int k0 = 0; k0 < K; k0 += 32) {
        __syncthreads();
        *(short8*)&As[sr][sk] = av;
        *(short8*)&Ws[sr][sk] = wv;
        if (k0 + 32 < K) {
            av = *(const short8*)&A[(size_t)ga * K + k0 + 32 + sk];
            wv = *(const short8*)&Wt[(size_t)(n0 + sr) * K + k0 + 32 + sk];
        }
        __syncthreads();
        short8 af0 = *(const short8*)&As[wm + c16][quad * 8];
        short8 af1 = *(const short8*)&As[wm + 16 + c16][quad * 8];
        short8 bf0 = *(const short8*)&Ws[wn + c16][quad * 8];
        short8 bf1 = *(const short8*)&Ws[wn + 16 + c16][quad * 8];
        acc[0][0] = __builtin_amdgcn_mfma_f32_16x16x32_bf16(af0, bf0, acc[0][0], 0, 0, 0);
        acc[0][1] = __builtin_amdgcn_mfma_f32_16x16x32_bf16(af0, bf1, acc[0][1], 0, 0, 0);
        acc[1][0] = __builtin_amdgcn_mfma_f32_16x16x32_bf16(af1, bf0, acc[1][0], 0, 0, 0);
        acc[1][1] = __builtin_amdgcn_mfma_f32_16x16x32_bf16(af1, bf1, acc[1][1], 0, 0, 0);
    }
    #pragma unroll
    for (int mb = 0; mb < 2; ++mb) {
        #pragma unroll
        for (int nb = 0; nb < 2; ++nb) {
            #pragma unroll
            for (int r = 0; r < 4; ++r) {
                int m = m0 + wm + mb * 16 + quad * 4 + r;
                if (m >= M) continue;
                int n = n0 + wn + nb * 16 + c16;
                float v = acc[mb][nb][r];
                if (bias) v += bias[n];
                if (flags & 1) v = 0.5f * v * (1.f + erff(v * 0.70710678118654752f));
                if (res) v += res[(size_t)m * Nn + n];
                if (flags & 2) ((short*)Cc)[(size_t)m * Nn + n] = f2bf(v);
                else           ((float*)Cc)[(size_t)m * Nn + n] = v;
            }
        }
    }
}

// ---------------------------------------------------------------------------
// V transpose: kv(b,n,512) cols 256..511 -> vt(bh, 32, NPAD) bf16.
// ---------------------------------------------------------------------------
__global__ __launch_bounds__(256) void vtrans_kernel(
    const short* __restrict__ kvb, short* __restrict__ vtb)
{
    __shared__ short S[64][33];
    int n0 = blockIdx.x * 64;
    int bh = blockIdx.y;
    int b = bh >> 3, h = bh & 7;
    int t = threadIdx.x;
    int d = t & 31, i0 = t >> 5;
    #pragma unroll
    for (int ii = 0; ii < 8; ++ii) {
        int n = n0 + i0 + ii * 8;
        short v = 0;
        if (n < N_) v = kvb[((size_t)(b * N_ + n)) * 512 + 256 + h * 32 + d];
        S[i0 + ii * 8][d] = v;
    }
    __syncthreads();
    int nl = t & 63, d0 = t >> 6;
    #pragma unroll
    for (int jj = 0; jj < 8; ++jj) {
        int dd = d0 + jj * 4;
        vtb[(size_t)bh * 32 * NPAD + (size_t)dd * NPAD + n0 + nl] = S[nl][dd];
    }
}

// ---------------------------------------------------------------------------
// MFMA attention, all-bf16 I/O + bitmask. 4 waves x 16 Q-rows, TN=64.
// pass1: L1/L2 per row (max-free softmax-1); pass2: weights + PV.
// Pipelined: next tile's global loads issue between the two barriers so
// HBM latency hides under the MFMA/expf phase. Pass2 runs with only 2
// barriers/iter: the P tile is per-wave, so wave-internal lgkmcnt ordering
// covers the P write->read; Vs stability is covered by the top barrier.
// ---------------------------------------------------------------------------
__global__ __launch_bounds__(256) void attn_mfma_kernel(
    const short* __restrict__ qb,   // (B, HW, 256) bf16, SCALE pre-folded
    const short* __restrict__ kvb,  // (B, N, 512) bf16, K = cols 0..255
    const short* __restrict__ vtb,  // (16, 32, NPAD) bf16 V^T
    const u64*  __restrict__ mbits, // (16, N, 37) keep bits
    short* __restrict__ ob)         // (B, HW, 256) bf16
{
    __shared__ short Ks[64][40];       // K chunk [n][d]
    __shared__ short Vs[32][72];       // V chunk transposed [d][n]
    __shared__ short Ps[4][16][72];    // per-wave P tile [m][n]

    const int t = threadIdx.x;
    const int w = t >> 6, l = t & 63;
    const int quad = l >> 4, c16 = l & 15;
    const int bh = blockIdx.y;
    const int b = bh >> 3, h = bh & 7;
    const int mw = blockIdx.x * 64 + w * 16;   // wave's first spatial row
    const f32x4 cz = {0.f, 0.f, 0.f, 0.f};

    // Q A-fragment (bf16 direct, scale already folded into Wq)
    const short8 aq = *(const short8*)
        &qb[((size_t)(b * HW_ + mw + c16)) * C_ + h * HD_ + quad * 8];

    const int sn = t >> 2;           // K staging row 0..63
    const int sd = (t & 3) * 8;      // K staging d-offset
    const int vd = t >> 3;           // V staging d 0..31
    const int vj = (t & 7) * 8;      // V staging j-offset

    // ---- pass 1: softmax-1 denominators ----
    float l1[4] = {0.f, 0.f, 0.f, 0.f}, l2[4] = {0.f, 0.f, 0.f, 0.f};
    short8 kk = {0, 0, 0, 0, 0, 0, 0, 0};
    if (sn < N_)
        kk = *(const short8*)&kvb[((size_t)(b * N_ + sn)) * 512 + h * HD_ + sd];
    for (int j0 = 0; j0 < N_; j0 += 64) {
        __syncthreads();
        *(short8*)&Ks[sn][sd] = kk;
        if (j0 + 64 < N_) {
            int gn = j0 + 64 + sn;
            short8 nk = {0, 0, 0, 0, 0, 0, 0, 0};
            if (gn < N_)
                nk = *(const short8*)&kvb[((size_t)(b * N_ + gn)) * 512 + h * HD_ + sd];
            kk = nk;
        }
        __syncthreads();
        #pragma unroll
        for (int nb = 0; nb < 4; ++nb) {
            short8 bk = *(const short8*)&Ks[nb * 16 + c16][quad * 8];
            f32x4 c = __builtin_amdgcn_mfma_f32_16x16x32_bf16(aq, bk, cz, 0, 0, 0);
            int j = j0 + nb * 16 + c16;
            #pragma unroll
            for (int r = 0; r < 4; ++r) {
                float e = (j < N_) ? __expf(c[r]) : 0.f;
                if (j < CLS_) l1[r] += e; else l2[r] += e;
            }
        }
    }
    float i1[4], i2[4];
    #pragma unroll
    for (int r = 0; r < 4; ++r) {
        float a = l1[r], s = l2[r];
        #pragma unroll
        for (int off = 1; off < 16; off <<= 1) {
            a += __shfl_xor(a, off, 64);
            s += __shfl_xor(s, off, 64);
        }
        i1[r] = 1.f / a;
        i2[r] = 1.f / s;
    }

    // ---- pass 2: weights, mask bits, PV ----
    f32x4 o0 = cz, o1 = cz;
    float zz[4] = {0.f, 0.f, 0.f, 0.f};
    const u64* mbase = mbits + ((size_t)bh * N_ + (CLS_ + mw + quad * 4)) * NT64;
    const size_t vrow = (size_t)bh * 32 * NPAD + (size_t)vd * NPAD + vj;
    short8 kk2 = {0, 0, 0, 0, 0, 0, 0, 0};
    if (sn < N_)
        kk2 = *(const short8*)&kvb[((size_t)(b * N_ + sn)) * 512 + h * HD_ + sd];
    short8 vv = *(const short8*)&vtb[vrow];
    for (int j0 = 0; j0 < N_; j0 += 64) {
        __syncthreads();
        *(short8*)&Ks[sn][sd] = kk2;
        *(short8*)&Vs[vd][vj] = vv;
        if (j0 + 64 < N_) {
            int gn = j0 + 64 + sn;
            short8 nk = {0, 0, 0, 0, 0, 0, 0, 0};
            if (gn < N_)
                nk = *(const short8*)&kvb[((size_t)(b * N_ + gn)) * 512 + h * HD_ + sd];
            kk2 = nk;
            vv = *(const short8*)&vtb[vrow + j0 + 64];
        }
        u64 wb[4];
        {
            const u64* mp = mbase + (j0 >> 6);
            #pragma unroll
            for (int r = 0; r < 4; ++r) wb[r] = mp[(size_t)r * NT64];
        }
        __syncthreads();
        #pragma unroll
        for (int nb = 0; nb < 4; ++nb) {
            short8 bk = *(const short8*)&Ks[nb * 16 + c16][quad * 8];
            f32x4 c = __builtin_amdgcn_mfma_f32_16x16x32_bf16(aq, bk, cz, 0, 0, 0);
            int j = j0 + nb * 16 + c16;
            #pragma unroll
            for (int r = 0; r < 4; ++r) {
                float iv = (j < CLS_) ? i1[r] : i2[r];
                float p = __expf(c[r]) * iv;
                bool keep = (wb[r] >> (nb * 16 + c16)) & 1;
                float wgt = keep ? __expf(p) : 0.f;
                zz[r] += wgt;
                Ps[w][quad * 4 + r][nb * 16 + c16] = f2bf(wgt);
            }
        }
        // no barrier: Ps[w] is wave-private (lgkmcnt orders write->read);
        // Vs was written this iter before the staging barrier above.
        #pragma unroll
        for (int kc = 0; kc < 2; ++kc) {
            short8 ap  = *(const short8*)&Ps[w][c16][kc * 32 + quad * 8];
            short8 bv0 = *(const short8*)&Vs[c16][kc * 32 + quad * 8];
            short8 bv1 = *(const short8*)&Vs[16 + c16][kc * 32 + quad * 8];
            o0 = __builtin_amdgcn_mfma_f32_16x16x32_bf16(ap, bv0, o0, 0, 0, 0);
            o1 = __builtin_amdgcn_mfma_f32_16x16x32_bf16(ap, bv1, o1, 0, 0, 0);
        }
    }
    #pragma unroll
    for (int r = 0; r < 4; ++r) {
        float z = zz[r];
        #pragma unroll
        for (int off = 1; off < 16; off <<= 1) z += __shfl_xor(z, off, 64);
        float iz = 1.f / z;
        size_t orow = (size_t)(b * HW_ + mw + quad * 4 + r) * C_ + h * HD_;
        ob[orow + c16]      = f2bf(o0[r] * iz);
        ob[orow + 16 + c16] = f2bf(o1[r] * iz);
    }
}

// ---------------------------------------------------------------------------
// (B, HW, C) fp32 -> (B, C, H, W) transpose, LDS-tiled.
// ---------------------------------------------------------------------------
__global__ __launch_bounds__(256) void transpose_kernel(
    const float* __restrict__ y, float* __restrict__ out)
{
    __shared__ float tile[64][65];
    int n0 = blockIdx.x * 64, c0 = blockIdx.y * 64, b = blockIdx.z;
    int lc = threadIdx.x & 63, lr = threadIdx.x >> 6;
    #pragma unroll
    for (int i = lr; i < 64; i += 4)
        tile[lc][i] = y[((size_t)(b * HW_ + n0 + i)) * C_ + c0 + lc];
    __syncthreads();
    #pragma unroll
    for (int i = lr; i < 64; i += 4)
        out[((size_t)(b * C_ + c0 + i)) * HW_ + n0 + lc] = tile[i][lc];
}

// ---------------------------------------------------------------------------
extern "C" void kernel_launch(void* const* d_in, const int* in_sizes, int n_in,
                              void* d_out, int out_size, void* d_ws, size_t ws_size,
                              hipStream_t stream)
{
    const float* x_query = (const float*)d_in[0];
    const float* x_key   = (const float*)d_in[1];
    const float* mask_u  = (const float*)d_in[2];
    const float* g1  = (const float*)d_in[3];
    const float* be1 = (const float*)d_in[4];
    const float* g2  = (const float*)d_in[5];
    const float* be2 = (const float*)d_in[6];
    const float* g3  = (const float*)d_in[7];
    const float* be3 = (const float*)d_in[8];
    const float* Wq  = (const float*)d_in[9];
    const float* Wkv = (const float*)d_in[10];
    // d_in[11] = Wcls: dead (rows < CLS sliced away after Wp)
    const float* Wp  = (const float*)d_in[12];
    const float* bp  = (const float*)d_in[13];
    const float* W1  = (const float*)d_in[14];
    const float* bf1 = (const float*)d_in[15];
    const float* W2  = (const float*)d_in[16];
    const float* bf2 = (const float*)d_in[17];
    float* out = (float*)d_out;

    // workspace layout (bytes), with aliasing of dead buffers
    char* p = (char*)d_ws;
    short* Wq_t  = (short*)p; p += (size_t)256 * 256 * 2;
    short* Wkv_t = (short*)p; p += (size_t)512 * 256 * 2;
    short* Wp_t  = (short*)p; p += (size_t)256 * 256 * 2;
    short* W1_t  = (short*)p; p += (size_t)1024 * 256 * 2;
    short* W2_t  = (short*)p; p += (size_t)256 * 1024 * 2;
    u64*  mbits  = (u64*)p;   p += (size_t)16 * N_ * NT64 * 8;   // 11.0 MB
    float* xq_t  = (float*)p; p += (size_t)B_ * HW_ * C_ * 4;
    short* q_in  = (short*)p; p += (size_t)B_ * HW_ * C_ * 2;
    short* k_in  = (short*)p; p += (size_t)B_ * N_ * C_ * 2;
    short* q_buf = (short*)p; p += (size_t)B_ * HW_ * C_ * 2;
    short* kv_b  = (short*)p; p += (size_t)B_ * N_ * 512 * 2;
    short* vt_b  = (short*)p; p += (size_t)16 * 32 * NPAD * 2;
    float* xq2   = (float*)p; p += (size_t)B_ * HW_ * C_ * 4;
    // aliases (dead-buffer reuse):
    short* o_buf = q_in;            // q_in dead after Wq GEMM
    short* ln3   = k_in;            // k_in dead after Wkv GEMM
    short* h_buf = (short*)mbits;   // mbits dead after attention (9.4 <= 11.0 MB)
    float* y_buf = (float*)q_buf;   // q_buf+kv_b dead after attention (4.7 <= 7.1 MB)

    // 0. weight prep (transpose + bf16; SCALE folded into Wq) — one launch
    wtrans_all_kernel<<<768, 256, 0, stream>>>(
        Wq, Wkv, Wp, W1, W2, Wq_t, Wkv_t, Wp_t, W1_t, W2_t);
    // 0b. mask -> keep bitmask (the big streaming read)
    mask_compress_kernel<<<(16 * N_) / 4, 256, 0, stream>>>(mask_u, mbits);
    // 1. LN(xq) with transpose; bf16 ln out + fp32 raw
    lnq_kernel<<<B_ * HW_, 256, 0, stream>>>(x_query, g1, be1, q_in, xq_t);
    // 2. LN(x_key) -> bf16
    ln_rows_kernel<<<B_ * N_, 256, 0, stream>>>(x_key, g2, be2, k_in);
    // 3. q_buf = q_in @ Wq (bf16 out)
    gemm_bf16_kernel<<<dim3(C_ / 64, (B_ * HW_) / 64), 256, 0, stream>>>(
        q_in, Wq_t, q_buf, B_ * HW_, C_, C_, nullptr, nullptr, 2);
    // 4. kv = k_in @ Wkv (bf16 out)
    gemm_bf16_kernel<<<dim3(512 / 64, (B_ * N_ + 63) / 64), 256, 0, stream>>>(
        k_in, Wkv_t, kv_b, B_ * N_, 512, C_, nullptr, nullptr, 2);
    // 4b. V^T
    vtrans_kernel<<<dim3(NT64, 16), 256, 0, stream>>>(kv_b, vt_b);
    // 5. attention -> o_buf (bf16)
    attn_mfma_kernel<<<dim3(HW_ / 64, B_ * HDS_), 256, 0, stream>>>(
        q_buf, kv_b, vt_b, mbits, o_buf);
    // 6. xq2 = o_buf @ Wp + bp + xq_t (fp32 out)
    gemm_bf16_kernel<<<dim3(C_ / 64, (B_ * HW_) / 64), 256, 0, stream>>>(
        o_buf, Wp_t, xq2, B_ * HW_, C_, C_, bp, xq_t, 0);
    // 7. ln3 = LN(xq2) -> bf16
    ln_rows_kernel<<<B_ * HW_, 256, 0, stream>>>(xq2, g3, be3, ln3);
    // 8. h = gelu(ln3 @ W1 + bf1) (bf16 out; aliases mbits)
    gemm_bf16_kernel<<<dim3(1024 / 64, (B_ * HW_) / 64), 256, 0, stream>>>(
        ln3, W1_t, h_buf, B_ * HW_, 1024, C_, bf1, nullptr, 3);
    // 9. y = h @ W2 + bf2 + xq2 (fp32 out)
    gemm_bf16_kernel<<<dim3(C_ / 64, (B_ * HW_) / 64), 256, 0, stream>>>(
        h_buf, W2_t, y_buf, B_ * HW_, C_, 1024, bf2, xq2, 0);
    // 10. (B,HW,C) -> (B,C,H,W)
    transpose_kernel<<<dim3(HW_ / 64, C_ / 64, B_), 256, 0, stream>>>(y_buf, out);
}

// Round 3
// 663.585 us; speedup vs baseline: 1.0857x; 1.0385x over previous
//
#include <hip/hip_runtime.h>
#include <hip/hip_bf16.h>
#include <cstddef>

// Problem constants
#define B_ 2
#define C_ 256
#define HW_ 2304      // H*W = 48*48
#define CLS_ 20
#define N_ 2324       // CLS + HW
#define HDS_ 8
#define HD_ 32
#define SCALE_F 0.17677669529663687f
#define LOG2E_F 1.4426950408889634f
#define QSCALE_F (SCALE_F * LOG2E_F)   // exp2-domain scores
#define MR_ 0.3f
#define EPS_ 1e-5f
#define NT64 37        // ceil(N/64) 64-col tiles
#define NPAD 2368      // 37*64
#define JTAIL 2304     // last 64-col tile start

typedef __attribute__((ext_vector_type(8))) short short8;
typedef __attribute__((ext_vector_type(4))) float f32x4;
typedef unsigned long long u64;

__device__ __forceinline__ short f2bf(float x) {
    union { __hip_bfloat16 b; short s; } u;
    u.b = __float2bfloat16(x);
    return u.s;
}
// raw v_exp_f32 (2^x); scores are pre-folded into log2 domain
__device__ __forceinline__ float fexp2(float x) {
    float r;
    asm volatile("v_exp_f32 %0, %1" : "=v"(r) : "v"(x));
    return r;
}
__device__ __forceinline__ u64 shfl_xor_u64(u64 v, int m) {
    unsigned lo = (unsigned)v, hi = (unsigned)(v >> 32);
    lo = (unsigned)__shfl_xor((int)lo, m, 64);
    hi = (unsigned)__shfl_xor((int)hi, m, 64);
    return ((u64)hi << 32) | lo;
}

// ---------------------------------------------------------------------------
// Merged weight transpose + bf16 convert: all 5 weights in one launch.
// W[K][N] -> Wt[N][K], scaled. 768 blocks total, range-dispatched.
// Wq gets SCALE*log2e so attention scores are in exp2 domain.
// ---------------------------------------------------------------------------
__global__ __launch_bounds__(256) void wtrans_all_kernel(
    const float* __restrict__ Wq,  const float* __restrict__ Wkv,
    const float* __restrict__ Wp,  const float* __restrict__ W1,
    const float* __restrict__ W2,
    short* __restrict__ Wq_t, short* __restrict__ Wkv_t,
    short* __restrict__ Wp_t, short* __restrict__ W1_t,
    short* __restrict__ W2_t)
{
    __shared__ float S[32][33];
    int bid = blockIdx.x;
    const float* W; short* Wt; int K, Nn; float scale;
    if (bid < 64)       { W = Wq;  Wt = Wq_t;  K = 256;  Nn = 256;  scale = QSCALE_F; }
    else if (bid < 192) { bid -= 64;  W = Wkv; Wt = Wkv_t; K = 256;  Nn = 512;  scale = 1.f; }
    else if (bid < 256) { bid -= 192; W = Wp;  Wt = Wp_t;  K = 256;  Nn = 256;  scale = 1.f; }
    else if (bid < 512) { bid -= 256; W = W1;  Wt = W1_t;  K = 256;  Nn = 1024; scale = 1.f; }
    else                { bid -= 512; W = W2;  Wt = W2_t;  K = 1024; Nn = 256;  scale = 1.f; }
    int nblk = Nn / 32;
    int n0 = (bid % nblk) * 32, k0 = (bid / nblk) * 32;
    int t = threadIdx.x;
    int nl = t & 31, kq = t >> 5;
    #pragma unroll
    for (int ii = 0; ii < 4; ++ii) {
        int k = kq + ii * 8;
        S[k][nl] = W[(size_t)(k0 + k) * Nn + n0 + nl] * scale;
    }
    __syncthreads();
    int kl = t & 31, nq = t >> 5;
    #pragma unroll
    for (int ii = 0; ii < 4; ++ii) {
        int n = nq + ii * 8;
        Wt[(size_t)(n0 + n) * K + k0 + kl] = f2bf(S[kl][n]);
    }
}

// ---------------------------------------------------------------------------
// Mask compress: (16, N, N) fp32 -> keep-bitmask (16, N, 37) uint64.
// bit=1 means keep (u >= MR). Cols >= N_ get 0. One wave per row.
// ---------------------------------------------------------------------------
__global__ __launch_bounds__(256) void mask_compress_kernel(
    const float* __restrict__ mask, u64* __restrict__ mbits)
{
    int rid = blockIdx.x * 4 + (threadIdx.x >> 6);   // (bh*N + row)
    int l = threadIdx.x & 63;
    const float* mrow = mask + (size_t)rid * N_;
    u64* orow = mbits + (size_t)rid * NT64;
    float4 uu[10];
    #pragma unroll
    for (int base = 0; base < 10; ++base) {
        int col = base * 256 + l * 4;
        if (col < N_) uu[base] = *(const float4*)&mrow[col];
        else { uu[base].x = -1.f; uu[base].y = -1.f; uu[base].z = -1.f; uu[base].w = -1.f; }
    }
    #pragma unroll
    for (int base = 0; base < 10; ++base) {
        float4 u = uu[base];
        unsigned nib = (u.x >= MR_ ? 1u : 0u) | (u.y >= MR_ ? 2u : 0u)
                     | (u.z >= MR_ ? 4u : 0u) | (u.w >= MR_ ? 8u : 0u);
        u64 part = (u64)nib << (4 * (l & 15));
        part |= shfl_xor_u64(part, 1);
        part |= shfl_xor_u64(part, 2);
        part |= shfl_xor_u64(part, 4);
        part |= shfl_xor_u64(part, 8);
        int widx = base * 4 + (l >> 4);
        if ((l & 15) == 0 && widx < NT64) orow[widx] = part;
    }
}

// ---------------------------------------------------------------------------
// Fused input LNs: blocks [0, B*HW) do x_query (NCHW gather + raw copy),
// blocks [B*HW, B*HW + B*N) do x_key rows. One launch.
// ---------------------------------------------------------------------------
__global__ __launch_bounds__(256) void ln_qk_kernel(
    const float* __restrict__ xq, const float* __restrict__ xk,
    const float* __restrict__ g1, const float* __restrict__ be1,
    const float* __restrict__ g2, const float* __restrict__ be2,
    short* __restrict__ q_ln, float* __restrict__ q_raw,
    short* __restrict__ k_ln)
{
    int row = blockIdx.x;
    int t = threadIdx.x;
    bool isq = row < B_ * HW_;
    float v;
    if (isq) {
        int b = row / HW_, n = row % HW_;
        v = xq[((size_t)(b * C_ + t)) * HW_ + n];
    } else {
        v = xk[(size_t)(row - B_ * HW_) * C_ + t];
    }
    float s = v, s2 = v * v;
    #pragma unroll
    for (int off = 1; off < 64; off <<= 1) {
        s  += __shfl_xor(s,  off, 64);
        s2 += __shfl_xor(s2, off, 64);
    }
    __shared__ float rs[4], rs2[4];
    int w = t >> 6;
    if ((t & 63) == 0) { rs[w] = s; rs2[w] = s2; }
    __syncthreads();
    s  = rs[0] + rs[1] + rs[2] + rs[3];
    s2 = rs2[0] + rs2[1] + rs2[2] + rs2[3];
    float mean = s * (1.f / 256.f);
    float var  = s2 * (1.f / 256.f) - mean * mean;
    float inv  = rsqrtf(var + EPS_);
    if (isq) {
        q_raw[(size_t)row * C_ + t] = v;
        q_ln [(size_t)row * C_ + t] = f2bf((v - mean) * inv * g1[t] + be1[t]);
    } else {
        k_ln[(size_t)(row - B_ * HW_) * C_ + t] =
            f2bf((v - mean) * inv * g2[t] + be2[t]);
    }
}

// ---------------------------------------------------------------------------
// LN over last dim 256, fp32 in -> bf16 out (used for post-attn LN).
// ---------------------------------------------------------------------------
__global__ __launch_bounds__(256) void ln_rows_kernel(
    const float* __restrict__ x, const float* __restrict__ g,
    const float* __restrict__ be, short* __restrict__ y)
{
    int row = blockIdx.x;
    int t = threadIdx.x;
    float v = x[(size_t)row * C_ + t];
    float s = v, s2 = v * v;
    #pragma unroll
    for (int off = 1; off < 64; off <<= 1) {
        s  += __shfl_xor(s,  off, 64);
        s2 += __shfl_xor(s2, off, 64);
    }
    __shared__ float rs[4], rs2[4];
    int w = t >> 6;
    if ((t & 63) == 0) { rs[w] = s; rs2[w] = s2; }
    __syncthreads();
    s  = rs[0] + rs[1] + rs[2] + rs[3];
    s2 = rs2[0] + rs2[1] + rs2[2] + rs2[3];
    float mean = s * (1.f / 256.f);
    float var  = s2 * (1.f / 256.f) - mean * mean;
    float inv  = rsqrtf(var + EPS_);
    y[(size_t)row * C_ + t] = f2bf((v - mean) * inv * g[t] + be[t]);
}

// ---------------------------------------------------------------------------
// bf16 MFMA GEMM: C[M,N] = A[M,K]@Wt[N,K]^T. 64x64 tile, BK=64, 4 waves,
// register-prefetch pipeline (next K-tile loads issued before compute
// barrier). flags: 1 = gelu, 2 = bf16 out, 4 = fp32 NCHW-transposed out.
// ---------------------------------------------------------------------------
__global__ __launch_bounds__(256) void gemm_bf16_kernel(
    const short* __restrict__ A, const short* __restrict__ Wt,
    void* __restrict__ Cc, int M, int Nn, int K,
    const float* __restrict__ bias, const float* __restrict__ res, int flags)
{
    __shared__ short As[64][72];   // [m][k]
    __shared__ short Ws[64][72];   // [n][k]
    const int t = threadIdx.x, w = t >> 6, l = t & 63;
    const int quad = l >> 4, c16 = l & 15;
    const int m0 = blockIdx.y * 64, n0 = blockIdx.x * 64;
    const int wm = (w >> 1) * 32, wn = (w & 1) * 32;
    const int sr = t >> 3;           // 0..31
    const int sk = (t & 7) * 8;      // 0..56
    const f32x4 cz = {0.f, 0.f, 0.f, 0.f};
    f32x4 acc[2][2] = {{cz, cz}, {cz, cz}};
    int ga0 = m0 + sr;      if (ga0 >= M) ga0 = M - 1;  // clamp; garbage unused
    int ga1 = m0 + 32 + sr; if (ga1 >= M) ga1 = M - 1;
    short8 av0 = *(const short8*)&A[(size_t)ga0 * K + sk];
    short8 av1 = *(const short8*)&A[(size_t)ga1 * K + sk];
    short8 wv0 = *(const short8*)&Wt[(size_t)(n0 + sr) * K + sk];
    short8 wv1 = *(const short8*)&Wt[(size_t)(n0 + 32 + sr) * K + sk];
    for (int k0 = 0; k0 < K; k0 += 64) {
        __syncthreads();
        *(short8*)&As[sr][sk]      = av0;
        *(short8*)&As[sr + 32][sk] = av1;
        *(short8*)&Ws[sr][sk]      = wv0;
        *(short8*)&Ws[sr + 32][sk] = wv1;
        if (k0 + 64 < K) {
            av0 = *(const short8*)&A[(size_t)ga0 * K + k0 + 64 + sk];
            av1 = *(const short8*)&A[(size_t)ga1 * K + k0 + 64 + sk];
            wv0 = *(const short8*)&Wt[(size_t)(n0 + sr) * K + k0 + 64 + sk];
            wv1 = *(const short8*)&Wt[(size_t)(n0 + 32 + sr) * K + k0 + 64 + sk];
        }
        __syncthreads();
        #pragma unroll
        for (int kk = 0; kk < 2; ++kk) {
            short8 af0 = *(const short8*)&As[wm + c16][kk * 32 + quad * 8];
            short8 af1 = *(const short8*)&As[wm + 16 + c16][kk * 32 + quad * 8];
            short8 bf0 = *(const short8*)&Ws[wn + c16][kk * 32 + quad * 8];
            short8 bf1 = *(const short8*)&Ws[wn + 16 + c16][kk * 32 + quad * 8];
            acc[0][0] = __builtin_amdgcn_mfma_f32_16x16x32_bf16(af0, bf0, acc[0][0], 0, 0, 0);
            acc[0][1] = __builtin_amdgcn_mfma_f32_16x16x32_bf16(af0, bf1, acc[0][1], 0, 0, 0);
            acc[1][0] = __builtin_amdgcn_mfma_f32_16x16x32_bf16(af1, bf0, acc[1][0], 0, 0, 0);
            acc[1][1] = __builtin_amdgcn_mfma_f32_16x16x32_bf16(af1, bf1, acc[1][1], 0, 0, 0);
        }
    }
    #pragma unroll
    for (int mb = 0; mb < 2; ++mb) {
        #pragma unroll
        for (int nb = 0; nb < 2; ++nb) {
            #pragma unroll
            for (int r = 0; r < 4; ++r) {
                int m = m0 + wm + mb * 16 + quad * 4 + r;
                if (m >= M) continue;
                int n = n0 + wn + nb * 16 + c16;
                float v = acc[mb][nb][r];
                if (bias) v += bias[n];
                if (flags & 1) v = 0.5f * v * (1.f + erff(v * 0.70710678118654752f));
                if (res) v += res[(size_t)m * Nn + n];
                if (flags & 4) {
                    int bb = (m >= HW_) ? 1 : 0;
                    int hw = m - bb * HW_;
                    ((float*)Cc)[((size_t)(bb * Nn + n)) * HW_ + hw] = v;
                } else if (flags & 2) {
                    ((short*)Cc)[(size_t)m * Nn + n] = f2bf(v);
                } else {
                    ((float*)Cc)[(size_t)m * Nn + n] = v;
                }
            }
        }
    }
}

// ---------------------------------------------------------------------------
// V transpose: kv(b,n,512) cols 256..511 -> vt(bh, 32, NPAD) bf16.
// ---------------------------------------------------------------------------
__global__ __launch_bounds__(256) void vtrans_kernel(
    const short* __restrict__ kvb, short* __restrict__ vtb)
{
    __shared__ short S[64][33];
    int n0 = blockIdx.x * 64;
    int bh = blockIdx.y;
    int b = bh >> 3, h = bh & 7;
    int t = threadIdx.x;
    int d = t & 31, i0 = t >> 5;
    #pragma unroll
    for (int ii = 0; ii < 8; ++ii) {
        int n = n0 + i0 + ii * 8;
        short v = 0;
        if (n < N_) v = kvb[((size_t)(b * N_ + n)) * 512 + 256 + h * 32 + d];
        S[i0 + ii * 8][d] = v;
    }
    __syncthreads();
    int nl = t & 63, d0 = t >> 6;
    #pragma unroll
    for (int jj = 0; jj < 8; ++jj) {
        int dd = d0 + jj * 4;
        vtb[(size_t)bh * 32 * NPAD + (size_t)dd * NPAD + n0 + nl] = S[nl][dd];
    }
}

// ---------------------------------------------------------------------------
// MFMA attention, exp2-domain scores, tile-specialized (first/mid/tail).
// 4 waves x 16 Q-rows, TN=64. pass1: L1/L2 per row; pass2: weights + PV.
// K/V/mask all register-prefetched one tile ahead; 2 barriers/iter.
// ---------------------------------------------------------------------------
__global__ __launch_bounds__(256) void attn_mfma_kernel(
    const short* __restrict__ qb,   // (B, HW, 256) bf16, SCALE*log2e pre-folded
    const short* __restrict__ kvb,  // (B, N, 512) bf16, K = cols 0..255
    const short* __restrict__ vtb,  // (16, 32, NPAD) bf16 V^T
    const u64*  __restrict__ mbits, // (16, N, 37) keep bits
    short* __restrict__ ob)         // (B, HW, 256) bf16
{
    __shared__ short Ks[64][40];       // K chunk [n][d]
    __shared__ short Vs[32][72];       // V chunk transposed [d][n]
    __shared__ short Ps[4][16][72];    // per-wave P tile [m][n]

    const int t = threadIdx.x;
    const int w = t >> 6, l = t & 63;
    const int quad = l >> 4, c16 = l & 15;
    const int bh = blockIdx.y;
    const int b = bh >> 3, h = bh & 7;
    const int mw = blockIdx.x * 64 + w * 16;   // wave's first spatial row
    const f32x4 cz = {0.f, 0.f, 0.f, 0.f};

    const short8 aq = *(const short8*)
        &qb[((size_t)(b * HW_ + mw + c16)) * C_ + h * HD_ + quad * 8];

    const int sn = t >> 2;           // K staging row 0..63
    const int sd = (t & 3) * 8;      // K staging d-offset
    const int vd = t >> 3;           // V staging d 0..31
    const int vj = (t & 7) * 8;      // V staging j-offset

    // ---- pass 1: softmax-1 denominators (exp2 domain) ----
    float l1[4] = {0.f, 0.f, 0.f, 0.f}, l2[4] = {0.f, 0.f, 0.f, 0.f};
    short8 kk = *(const short8*)&kvb[((size_t)(b * N_ + sn)) * 512 + h * HD_ + sd];
    for (int j0 = 0; j0 < N_; j0 += 64) {
        __syncthreads();
        *(short8*)&Ks[sn][sd] = kk;
        if (j0 + 64 < N_) {
            int gn = j0 + 64 + sn;
            short8 nk = {0, 0, 0, 0, 0, 0, 0, 0};
            if (gn < N_)
                nk = *(const short8*)&kvb[((size_t)(b * N_ + gn)) * 512 + h * HD_ + sd];
            kk = nk;
        }
        __syncthreads();
        if (j0 == 0) {
            // tile 0: CLS boundary at 20 (nb0 all cls, nb1 split, nb2/3 spatial)
            #pragma unroll
            for (int nb = 0; nb < 4; ++nb) {
                short8 bk = *(const short8*)&Ks[nb * 16 + c16][quad * 8];
                f32x4 c = __builtin_amdgcn_mfma_f32_16x16x32_bf16(aq, bk, cz, 0, 0, 0);
                #pragma unroll
                for (int r = 0; r < 4; ++r) {
                    float e = fexp2(c[r]);
                    if (nb == 0)      l1[r] += e;
                    else if (nb == 1) { bool cl = c16 < 4; l1[r] += cl ? e : 0.f; l2[r] += cl ? 0.f : e; }
                    else              l2[r] += e;
                }
            }
        } else if (j0 == JTAIL) {
            // tail: cols 2304..2323 valid (nb0 full, nb1 c16<4, nb2/3 dead)
            #pragma unroll
            for (int nb = 0; nb < 2; ++nb) {
                short8 bk = *(const short8*)&Ks[nb * 16 + c16][quad * 8];
                f32x4 c = __builtin_amdgcn_mfma_f32_16x16x32_bf16(aq, bk, cz, 0, 0, 0);
                #pragma unroll
                for (int r = 0; r < 4; ++r) {
                    float e = fexp2(c[r]);
                    if (nb == 0) l2[r] += e;
                    else         l2[r] += (c16 < 4) ? e : 0.f;
                }
            }
        } else {
            // clean mid tiles: no guards at all
            #pragma unroll
            for (int nb = 0; nb < 4; ++nb) {
                short8 bk = *(const short8*)&Ks[nb * 16 + c16][quad * 8];
                f32x4 c = __builtin_amdgcn_mfma_f32_16x16x32_bf16(aq, bk, cz, 0, 0, 0);
                #pragma unroll
                for (int r = 0; r < 4; ++r) l2[r] += fexp2(c[r]);
            }
        }
    }
    float i1[4], i2[4];
    #pragma unroll
    for (int r = 0; r < 4; ++r) {
        float a = l1[r], s = l2[r];
        #pragma unroll
        for (int off = 1; off < 16; off <<= 1) {
            a += __shfl_xor(a, off, 64);
            s += __shfl_xor(s, off, 64);
        }
        i1[r] = 1.f / a;
        i2[r] = 1.f / s;
    }

    // ---- pass 2: weights, mask bits, PV ----
    f32x4 o0 = cz, o1 = cz;
    float zz[4] = {0.f, 0.f, 0.f, 0.f};
    const u64* mbase = mbits + ((size_t)bh * N_ + (CLS_ + mw + quad * 4)) * NT64;
    const size_t vrow = (size_t)bh * 32 * NPAD + (size_t)vd * NPAD + vj;
    short8 kk2 = *(const short8*)&kvb[((size_t)(b * N_ + sn)) * 512 + h * HD_ + sd];
    short8 vv = *(const short8*)&vtb[vrow];
    u64 wb[4];
    #pragma unroll
    for (int r = 0; r < 4; ++r) wb[r] = mbase[(size_t)r * NT64];
    for (int j0 = 0; j0 < N_; j0 += 64) {
        __syncthreads();
        *(short8*)&Ks[sn][sd] = kk2;
        *(short8*)&Vs[vd][vj] = vv;
        u64 wbc[4];
        #pragma unroll
        for (int r = 0; r < 4; ++r) wbc[r] = wb[r];
        if (j0 + 64 < N_) {
            int gn = j0 + 64 + sn;
            short8 nk = {0, 0, 0, 0, 0, 0, 0, 0};
            if (gn < N_)
                nk = *(const short8*)&kvb[((size_t)(b * N_ + gn)) * 512 + h * HD_ + sd];
            kk2 = nk;
            vv = *(const short8*)&vtb[vrow + j0 + 64];
            const u64* mp = mbase + ((j0 + 64) >> 6);
            #pragma unroll
            for (int r = 0; r < 4; ++r) wb[r] = mp[(size_t)r * NT64];
        }
        __syncthreads();
        if (j0 == 0) {
            #pragma unroll
            for (int nb = 0; nb < 4; ++nb) {
                short8 bk = *(const short8*)&Ks[nb * 16 + c16][quad * 8];
                f32x4 c = __builtin_amdgcn_mfma_f32_16x16x32_bf16(aq, bk, cz, 0, 0, 0);
                #pragma unroll
                for (int r = 0; r < 4; ++r) {
                    float iv;
                    if (nb == 0)      iv = i1[r];
                    else if (nb == 1) iv = (c16 < 4) ? i1[r] : i2[r];
                    else              iv = i2[r];
                    float p = fexp2(c[r]) * iv;
                    bool keep = (wbc[r] >> (nb * 16 + c16)) & 1;
                    float wgt = keep ? fexp2(p * LOG2E_F) : 0.f;
                    zz[r] += wgt;
                    Ps[w][quad * 4 + r][nb * 16 + c16] = f2bf(wgt);
                }
            }
        } else {
            // mid + tail share this path: keep-bits are 0 beyond N, so
            // out-of-range columns produce wgt=0 (Ps zeroed) automatically.
            #pragma unroll
            for (int nb = 0; nb < 4; ++nb) {
                short8 bk = *(const short8*)&Ks[nb * 16 + c16][quad * 8];
                f32x4 c = __builtin_amdgcn_mfma_f32_16x16x32_bf16(aq, bk, cz, 0, 0, 0);
                #pragma unroll
                for (int r = 0; r < 4; ++r) {
                    float p = fexp2(c[r]) * i2[r];
                    bool keep = (wbc[r] >> (nb * 16 + c16)) & 1;
                    float wgt = keep ? fexp2(p * LOG2E_F) : 0.f;
                    zz[r] += wgt;
                    Ps[w][quad * 4 + r][nb * 16 + c16] = f2bf(wgt);
                }
            }
        }
        // no barrier: Ps[w] is wave-private (lgkmcnt orders write->read);
        // Vs was written this iter before the staging barrier above.
        #pragma unroll
        for (int kc = 0; kc < 2; ++kc) {
            short8 ap  = *(const short8*)&Ps[w][c16][kc * 32 + quad * 8];
            short8 bv0 = *(const short8*)&Vs[c16][kc * 32 + quad * 8];
            short8 bv1 = *(const short8*)&Vs[16 + c16][kc * 32 + quad * 8];
            o0 = __builtin_amdgcn_mfma_f32_16x16x32_bf16(ap, bv0, o0, 0, 0, 0);
            o1 = __builtin_amdgcn_mfma_f32_16x16x32_bf16(ap, bv1, o1, 0, 0, 0);
        }
    }
    #pragma unroll
    for (int r = 0; r < 4; ++r) {
        float z = zz[r];
        #pragma unroll
        for (int off = 1; off < 16; off <<= 1) z += __shfl_xor(z, off, 64);
        float iz = 1.f / z;
        size_t orow = (size_t)(b * HW_ + mw + quad * 4 + r) * C_ + h * HD_;
        ob[orow + c16]      = f2bf(o0[r] * iz);
        ob[orow + 16 + c16] = f2bf(o1[r] * iz);
    }
}

// ---------------------------------------------------------------------------
extern "C" void kernel_launch(void* const* d_in, const int* in_sizes, int n_in,
                              void* d_out, int out_size, void* d_ws, size_t ws_size,
                              hipStream_t stream)
{
    const float* x_query = (const float*)d_in[0];
    const float* x_key   = (const float*)d_in[1];
    const float* mask_u  = (const float*)d_in[2];
    const float* g1  = (const float*)d_in[3];
    const float* be1 = (const float*)d_in[4];
    const float* g2  = (const float*)d_in[5];
    const float* be2 = (const float*)d_in[6];
    const float* g3  = (const float*)d_in[7];
    const float* be3 = (const float*)d_in[8];
    const float* Wq  = (const float*)d_in[9];
    const float* Wkv = (const float*)d_in[10];
    // d_in[11] = Wcls: dead (rows < CLS sliced away after Wp)
    const float* Wp  = (const float*)d_in[12];
    const float* bp  = (const float*)d_in[13];
    const float* W1  = (const float*)d_in[14];
    const float* bf1 = (const float*)d_in[15];
    const float* W2  = (const float*)d_in[16];
    const float* bf2 = (const float*)d_in[17];
    float* out = (float*)d_out;

    // workspace layout (bytes), with aliasing of dead buffers
    char* p = (char*)d_ws;
    short* Wq_t  = (short*)p; p += (size_t)256 * 256 * 2;
    short* Wkv_t = (short*)p; p += (size_t)512 * 256 * 2;
    short* Wp_t  = (short*)p; p += (size_t)256 * 256 * 2;
    short* W1_t  = (short*)p; p += (size_t)1024 * 256 * 2;
    short* W2_t  = (short*)p; p += (size_t)256 * 1024 * 2;
    u64*  mbits  = (u64*)p;   p += (size_t)16 * N_ * NT64 * 8;   // 11.0 MB
    float* xq_t  = (float*)p; p += (size_t)B_ * HW_ * C_ * 4;
    short* q_in  = (short*)p; p += (size_t)B_ * HW_ * C_ * 2;
    short* k_in  = (short*)p; p += (size_t)B_ * N_ * C_ * 2;
    short* q_buf = (short*)p; p += (size_t)B_ * HW_ * C_ * 2;
    short* kv_b  = (short*)p; p += (size_t)B_ * N_ * 512 * 2;
    short* vt_b  = (short*)p; p += (size_t)16 * 32 * NPAD * 2;
    float* xq2   = (float*)p; p += (size_t)B_ * HW_ * C_ * 4;
    // aliases (dead-buffer reuse):
    short* o_buf = q_in;            // q_in dead after Wq GEMM
    short* ln3   = k_in;            // k_in dead after Wkv GEMM
    short* h_buf = (short*)mbits;   // mbits dead after attention (9.4 <= 11.0 MB)

    // 0. weight prep (transpose + bf16; SCALE*log2e folded into Wq)
    wtrans_all_kernel<<<768, 256, 0, stream>>>(
        Wq, Wkv, Wp, W1, W2, Wq_t, Wkv_t, Wp_t, W1_t, W2_t);
    // 0b. mask -> keep bitmask (the big streaming read)
    mask_compress_kernel<<<(16 * N_) / 4, 256, 0, stream>>>(mask_u, mbits);
    // 1+2. fused LN(xq) with transpose + LN(x_key)
    ln_qk_kernel<<<B_ * HW_ + B_ * N_, 256, 0, stream>>>(
        x_query, x_key, g1, be1, g2, be2, q_in, xq_t, k_in);
    // 3. q_buf = q_in @ Wq (bf16 out)
    gemm_bf16_kernel<<<dim3(C_ / 64, (B_ * HW_) / 64), 256, 0, stream>>>(
        q_in, Wq_t, q_buf, B_ * HW_, C_, C_, nullptr, nullptr, 2);
    // 4. kv = k_in @ Wkv (bf16 out)
    gemm_bf16_kernel<<<dim3(512 / 64, (B_ * N_ + 63) / 64), 256, 0, stream>>>(
        k_in, Wkv_t, kv_b, B_ * N_, 512, C_, nullptr, nullptr, 2);
    // 4b. V^T
    vtrans_kernel<<<dim3(NT64, 16), 256, 0, stream>>>(kv_b, vt_b);
    // 5. attention -> o_buf (bf16)
    attn_mfma_kernel<<<dim3(HW_ / 64, B_ * HDS_), 256, 0, stream>>>(
        q_buf, kv_b, vt_b, mbits, o_buf);
    // 6. xq2 = o_buf @ Wp + bp + xq_t (fp32 out)
    gemm_bf16_kernel<<<dim3(C_ / 64, (B_ * HW_) / 64), 256, 0, stream>>>(
        o_buf, Wp_t, xq2, B_ * HW_, C_, C_, bp, xq_t, 0);
    // 7. ln3 = LN(xq2) -> bf16
    ln_rows_kernel<<<B_ * HW_, 256, 0, stream>>>(xq2, g3, be3, ln3);
    // 8. h = gelu(ln3 @ W1 + bf1) (bf16 out; aliases mbits)
    gemm_bf16_kernel<<<dim3(1024 / 64, (B_ * HW_) / 64), 256, 0, stream>>>(
        ln3, W1_t, h_buf, B_ * HW_, 1024, C_, bf1, nullptr, 3);
    // 9. out = (h @ W2 + bf2 + xq2) transposed to NCHW (fused final transpose)
    gemm_bf16_kernel<<<dim3(C_ / 64, (B_ * HW_) / 64), 256, 0, stream>>>(
        h_buf, W2_t, out, B_ * HW_, C_, 1024, bf2, xq2, 4);
}